// Round 2
// baseline (479.005 us; speedup 1.0000x reference)
//
#include <hip/hip_runtime.h>
#include <hip/hip_bf16.h>

// Problem constants
#define DIMK   512
#define HEADS  8
#define DHEAD  64
#define SEQ    2048
#define BATCH  8
#define MROWS  (BATCH*SEQ)      // 16384
#define SCALE_LOG2E (0.044194173824159216f * 1.44269504088896340736f) // 512^-0.5 * log2(e)

typedef float fx4   __attribute__((ext_vector_type(4)));
typedef short bf16x8 __attribute__((ext_vector_type(8)));
typedef short bf16x4 __attribute__((ext_vector_type(4)));

__device__ __forceinline__ short f2bf(float f) {
    union { float f; unsigned u; } x; x.f = f;
    unsigned r = (x.u + 0x7FFFu + ((x.u >> 16) & 1u)) >> 16;   // RNE
    return (short)r;
}

// ---------------------------------------------------------------- convert
// one float4 per thread; grid must be exactly nElems/4/256 blocks
__global__ __launch_bounds__(256) void cvt_kernel(const float* __restrict__ src,
                                                  short* __restrict__ dst) {
    int i = blockIdx.x * 256 + threadIdx.x;
    float4 v = ((const float4*)src)[i];
    bf16x4 o; o.x = f2bf(v.x); o.y = f2bf(v.y); o.z = f2bf(v.z); o.w = f2bf(v.w);
    ((bf16x4*)dst)[i] = o;
}

// ------------------------------------------------- weight transpose W[k][n] -> WT[n][k] bf16
__global__ __launch_bounds__(256) void wtrans_kernel(const float* __restrict__ Wq,
                                                     const float* __restrict__ Wk,
                                                     const float* __restrict__ Wv,
                                                     const float* __restrict__ Wo,
                                                     short* __restrict__ wT) {
    __shared__ float tile[32][33];
    const float* W = (blockIdx.z == 0) ? Wq : (blockIdx.z == 1) ? Wk
                   : (blockIdx.z == 2) ? Wv : Wo;
    short* dst = wT + (size_t)blockIdx.z * DIMK * DIMK;
    int n0 = blockIdx.x * 32, k0 = blockIdx.y * 32;
    int tx = threadIdx.x, ty = threadIdx.y;          // (32,8)
#pragma unroll
    for (int i = 0; i < 32; i += 8)
        tile[ty + i][tx] = W[(size_t)(k0 + ty + i) * DIMK + n0 + tx];
    __syncthreads();
#pragma unroll
    for (int i = 0; i < 32; i += 8)
        dst[(size_t)(n0 + ty + i) * DIMK + k0 + tx] = f2bf(tile[tx][ty + i]);
}

// ---------------------------------------------------------------- GEMM mainloop
// C(128x64) = A(128x512) @ BT(64x512)^T, bf16 in, fp32 acc. 4 waves, each 32x64.
__device__ __forceinline__ void gemm_mainloop(const short* __restrict__ Ablk,
                                              const short* __restrict__ Bblk,
                                              short* sA, short* sB, fx4 acc[2][4]) {
    int t = threadIdx.x;
    int w = t >> 6, lane = t & 63, quad = (lane >> 4), l15 = lane & 15;
    for (int k0 = 0; k0 < DIMK; k0 += 32) {
        __syncthreads();
        // stage A 128x32 (two passes), B 64x32
#pragma unroll
        for (int i = 0; i < 2; i++) {
            int row = i * 64 + (t >> 2), c = t & 3;
            *(bf16x8*)&sA[row * 32 + c * 8] =
                *(const bf16x8*)&Ablk[(size_t)row * DIMK + k0 + c * 8];
        }
        {
            int row = t >> 2, c = t & 3;
            *(bf16x8*)&sB[row * 32 + c * 8] =
                *(const bf16x8*)&Bblk[(size_t)row * DIMK + k0 + c * 8];
        }
        __syncthreads();
        bf16x8 a[2], b[4];
#pragma unroll
        for (int mt = 0; mt < 2; mt++)
            a[mt] = *(bf16x8*)&sA[(w * 32 + mt * 16 + l15) * 32 + quad * 8];
#pragma unroll
        for (int nt = 0; nt < 4; nt++)
            b[nt] = *(bf16x8*)&sB[(nt * 16 + l15) * 32 + quad * 8];
#pragma unroll
        for (int mt = 0; mt < 2; mt++)
#pragma unroll
            for (int nt = 0; nt < 4; nt++)
                acc[mt][nt] = __builtin_amdgcn_mfma_f32_16x16x32_bf16(
                    a[mt], b[nt], acc[mt][nt], 0, 0, 0);
    }
}

// ---------------------------------------------------------------- QKV projection
// mode(z): 0 -> q[bh][n][64], 1 -> k[bh][j][64], 2 -> vT[bh][64][2048]
__global__ __launch_bounds__(256) void proj_qkv(const short* __restrict__ xb,
                                                const short* __restrict__ mb,
                                                const short* __restrict__ wT,
                                                short* __restrict__ qkv) {
    __shared__ __attribute__((aligned(16))) short sA[128 * 32];
    __shared__ __attribute__((aligned(16))) short sB[64 * 32];
    int mode = blockIdx.z;
    const short* A  = ((mode == 0) ? xb : mb) + (size_t)blockIdx.x * 128 * DIMK;
    const short* BT = wT + (size_t)mode * DIMK * DIMK + (size_t)blockIdx.y * 64 * DIMK;
    fx4 acc[2][4] = {};
    gemm_mainloop(A, BT, sA, sB, acc);

    int t = threadIdx.x, w = t >> 6, lane = t & 63, quad = lane >> 4, l15 = lane & 15;
    int h = blockIdx.y;                              // 512 cols / 64 per block -> h == y
    short* dst = qkv + (size_t)mode * MROWS * DIMK;
#pragma unroll
    for (int mt = 0; mt < 2; mt++)
#pragma unroll
        for (int nt = 0; nt < 4; nt++)
#pragma unroll
            for (int r = 0; r < 4; r++) {
                int gm = blockIdx.x * 128 + w * 32 + mt * 16 + quad * 4 + r;
                int b = gm >> 11, n = gm & 2047;
                int d = nt * 16 + l15;
                short val = f2bf(acc[mt][nt][r]);
                if (mode < 2)
                    dst[(((size_t)(b * 8 + h) * SEQ + n) << 6) + d] = val;
                else
                    dst[(((size_t)(b * 8 + h) * DHEAD + d) << 11) + n] = val;
            }
}

// ---------------------------------------------------------------- output projection
__global__ __launch_bounds__(256) void out_proj(const short* __restrict__ ob,
                                                const short* __restrict__ woT,
                                                const float* __restrict__ bo,
                                                float* __restrict__ out) {
    __shared__ __attribute__((aligned(16))) short sA[128 * 32];
    __shared__ __attribute__((aligned(16))) short sB[64 * 32];
    const short* A  = ob + (size_t)blockIdx.x * 128 * DIMK;
    const short* BT = woT + (size_t)blockIdx.y * 64 * DIMK;
    fx4 acc[2][4] = {};
    gemm_mainloop(A, BT, sA, sB, acc);

    int t = threadIdx.x, w = t >> 6, lane = t & 63, quad = lane >> 4, l15 = lane & 15;
#pragma unroll
    for (int mt = 0; mt < 2; mt++)
#pragma unroll
        for (int nt = 0; nt < 4; nt++) {
            int gn = blockIdx.y * 64 + nt * 16 + l15;
            float bias = bo[gn];
#pragma unroll
            for (int r = 0; r < 4; r++) {
                int gm = blockIdx.x * 128 + w * 32 + mt * 16 + quad * 4 + r;
                out[(size_t)gm * DIMK + gn] = acc[mt][nt][r] + bias;
            }
        }
}

// ---------------------------------------------------------------- flash attention
// grid: (SEQ/64, BATCH*HEADS). block 256 = 4 waves; wave w owns q rows [i0+16w, i0+16w+16)
__global__ __launch_bounds__(256) void attn_kernel(const short* __restrict__ q,
                                                   const short* __restrict__ k,
                                                   const short* __restrict__ vt,
                                                   short* __restrict__ o) {
    __shared__ __attribute__((aligned(16))) short sQ[64 * 64];
    __shared__ __attribute__((aligned(16))) short sK[64 * 64];
    __shared__ __attribute__((aligned(16))) short sV[64 * 64];   // vT block [d][j]
    __shared__ __attribute__((aligned(16))) short sP[4][16 * 64];

    int t = threadIdx.x, w = t >> 6, lane = t & 63, quad = lane >> 4, l15 = lane & 15;
    int bh = blockIdx.y;
    int i0 = blockIdx.x * 64;
    const short* qbh = q  + (size_t)bh * SEQ * DHEAD;
    const short* kbh = k  + (size_t)bh * SEQ * DHEAD;
    const short* vbh = vt + (size_t)bh * DHEAD * SEQ;

    // stage Q (64x64)
#pragma unroll
    for (int i = 0; i < 2; i++) {
        int idx = i * 256 + t, row = idx >> 3, c = idx & 7;
        *(bf16x8*)&sQ[row * 64 + c * 8] =
            *(const bf16x8*)&qbh[(size_t)(i0 + row) * DHEAD + c * 8];
    }
    __syncthreads();
    bf16x8 aq[2];
    aq[0] = *(bf16x8*)&sQ[(w * 16 + l15) * 64 + quad * 8];
    aq[1] = *(bf16x8*)&sQ[(w * 16 + l15) * 64 + 32 + quad * 8];

    float mrun[4], lrun[4];
    fx4 oacc[4] = {};
#pragma unroll
    for (int r = 0; r < 4; r++) { mrun[r] = -1e30f; lrun[r] = 0.f; }

    for (int j0 = 0; j0 < SEQ; j0 += 64) {
        __syncthreads();   // prev iteration's sK/sV reads done
#pragma unroll
        for (int i = 0; i < 2; i++) {
            int idx = i * 256 + t, row = idx >> 3, c = idx & 7;
            *(bf16x8*)&sK[row * 64 + c * 8] =
                *(const bf16x8*)&kbh[(size_t)(j0 + row) * DHEAD + c * 8];
            *(bf16x8*)&sV[row * 64 + c * 8] =
                *(const bf16x8*)&vbh[(size_t)row * SEQ + j0 + c * 8];
        }
        __syncthreads();

        // S = Q @ K^T (16 x 64 per wave)
        fx4 s[4];
#pragma unroll
        for (int nt = 0; nt < 4; nt++) {
            fx4 a = {};
            bf16x8 b0 = *(bf16x8*)&sK[(nt * 16 + l15) * 64 + quad * 8];
            bf16x8 b1 = *(bf16x8*)&sK[(nt * 16 + l15) * 64 + 32 + quad * 8];
            a = __builtin_amdgcn_mfma_f32_16x16x32_bf16(aq[0], b0, a, 0, 0, 0);
            a = __builtin_amdgcn_mfma_f32_16x16x32_bf16(aq[1], b1, a, 0, 0, 0);
            s[nt] = a;
        }

        // online softmax (rows = quad*4+r, cols spread over 16 lanes)
        float rmax[4];
#pragma unroll
        for (int r = 0; r < 4; r++) {
            float v = s[0][r];
#pragma unroll
            for (int nt = 1; nt < 4; nt++) v = fmaxf(v, s[nt][r]);
            rmax[r] = v;
        }
#pragma unroll
        for (int off = 1; off < 16; off <<= 1)
#pragma unroll
            for (int r = 0; r < 4; r++)
                rmax[r] = fmaxf(rmax[r], __shfl_xor(rmax[r], off));

        float alpha[4];
#pragma unroll
        for (int r = 0; r < 4; r++) {
            float mn = fmaxf(mrun[r], rmax[r] * SCALE_LOG2E);
            alpha[r] = __builtin_amdgcn_exp2f(mrun[r] - mn);
            mrun[r] = mn;
        }
        float rsum[4] = {0.f, 0.f, 0.f, 0.f};
#pragma unroll
        for (int nt = 0; nt < 4; nt++)
#pragma unroll
            for (int r = 0; r < 4; r++) {
                float p = __builtin_amdgcn_exp2f(s[nt][r] * SCALE_LOG2E - mrun[r]);
                s[nt][r] = p;
                rsum[r] += p;
            }
#pragma unroll
        for (int off = 1; off < 16; off <<= 1)
#pragma unroll
            for (int r = 0; r < 4; r++)
                rsum[r] += __shfl_xor(rsum[r], off);
#pragma unroll
        for (int r = 0; r < 4; r++) lrun[r] = lrun[r] * alpha[r] + rsum[r];
#pragma unroll
        for (int dt = 0; dt < 4; dt++)
#pragma unroll
            for (int r = 0; r < 4; r++) oacc[dt][r] *= alpha[r];

        // P (C-layout) -> LDS -> A-layout
#pragma unroll
        for (int nt = 0; nt < 4; nt++)
#pragma unroll
            for (int r = 0; r < 4; r++)
                sP[w][(quad * 4 + r) * 64 + nt * 16 + l15] = f2bf(s[nt][r]);
        __syncthreads();
        bf16x8 ap0 = *(bf16x8*)&sP[w][l15 * 64 + quad * 8];
        bf16x8 ap1 = *(bf16x8*)&sP[w][l15 * 64 + 32 + quad * 8];

        // O += P @ V
#pragma unroll
        for (int dt = 0; dt < 4; dt++) {
            bf16x8 b0 = *(bf16x8*)&sV[(dt * 16 + l15) * 64 + quad * 8];
            bf16x8 b1 = *(bf16x8*)&sV[(dt * 16 + l15) * 64 + 32 + quad * 8];
            oacc[dt] = __builtin_amdgcn_mfma_f32_16x16x32_bf16(ap0, b0, oacc[dt], 0, 0, 0);
            oacc[dt] = __builtin_amdgcn_mfma_f32_16x16x32_bf16(ap1, b1, oacc[dt], 0, 0, 0);
        }
    }

    // epilogue: o[b][n][h*64+d] bf16
    int b = bh >> 3, h = bh & 7;
#pragma unroll
    for (int dt = 0; dt < 4; dt++)
#pragma unroll
        for (int r = 0; r < 4; r++) {
            int i = i0 + w * 16 + quad * 4 + r;
            float val = oacc[dt][r] / lrun[r];
            o[((size_t)(b * SEQ + i) * DIMK) + h * DHEAD + dt * 16 + l15] = f2bf(val);
        }
}

// ---------------------------------------------------------------- launch
extern "C" void kernel_launch(void* const* d_in, const int* in_sizes, int n_in,
                              void* d_out, int out_size, void* d_ws, size_t ws_size,
                              hipStream_t stream) {
    const float* x  = (const float*)d_in[0];
    const float* m  = (const float*)d_in[1];
    const float* Wq = (const float*)d_in[2];
    const float* Wk = (const float*)d_in[3];
    const float* Wv = (const float*)d_in[4];
    const float* Wo = (const float*)d_in[5];
    const float* bo = (const float*)d_in[6];
    float* out = (float*)d_out;

    char* ws = (char*)d_ws;
    const size_t XB_BYTES = (size_t)MROWS * DIMK * 2;      // 16 MiB
    short* xb  = (short*)(ws);
    short* mb  = (short*)(ws + XB_BYTES);
    short* wT  = (short*)(ws + 2 * XB_BYTES);              // 4 x 512x512 bf16 = 2 MiB
    short* qkv = (short*)(ws + 2 * XB_BYTES + 4 * (size_t)DIMK * DIMK * 2);
    short* ob  = xb;   // xb is dead after proj_qkv; reuse as attention output

    // x,m each have MROWS*DIMK = 8,388,608 floats = 2,097,152 float4 -> 8192 blocks
    const int CVT_BLOCKS = (MROWS * DIMK) / 4 / 256;       // 8192
    cvt_kernel<<<CVT_BLOCKS, 256, 0, stream>>>(x, xb);
    cvt_kernel<<<CVT_BLOCKS, 256, 0, stream>>>(m, mb);
    wtrans_kernel<<<dim3(16, 16, 4), dim3(32, 8), 0, stream>>>(Wq, Wk, Wv, Wo, wT);
    proj_qkv<<<dim3(128, 8, 3), 256, 0, stream>>>(xb, mb, wT, qkv);
    attn_kernel<<<dim3(SEQ / 64, BATCH * HEADS), 256, 0, stream>>>(
        qkv, qkv + (size_t)MROWS * DIMK, qkv + 2 * (size_t)MROWS * DIMK, ob);
    out_proj<<<dim3(128, 8), 256, 0, stream>>>(ob, wT + 3 * (size_t)DIMK * DIMK, bo, out);
}

// Round 3
// 307.298 us; speedup vs baseline: 1.5588x; 1.5588x over previous
//
#include <hip/hip_runtime.h>
#include <hip/hip_bf16.h>

// Problem constants
#define DIMK   512
#define HEADS  8
#define DHEAD  64
#define SEQ    2048
#define BATCH  8
#define MROWS  (BATCH*SEQ)      // 16384
#define SCALE_LOG2E (0.044194173824159216f * 1.44269504088896340736f) // 512^-0.5 * log2(e)
#define LDSS   72               // padded LDS row stride (shorts): 144B, 16B-aligned, bank-rotating

typedef float fx4   __attribute__((ext_vector_type(4)));
typedef short bf16x8 __attribute__((ext_vector_type(8)));
typedef short bf16x4 __attribute__((ext_vector_type(4)));

__device__ __forceinline__ short f2bf(float f) {
    union { float f; unsigned u; } x; x.f = f;
    unsigned r = (x.u + 0x7FFFu + ((x.u >> 16) & 1u)) >> 16;   // RNE
    return (short)r;
}

// pack two floats to two bf16 (round-half-up) in one dword: 3 VALU via v_perm_b32
__device__ __forceinline__ unsigned pk2bf(float a, float b) {
    union { float f; unsigned u; } A, B; A.f = a; B.f = b;
    return __builtin_amdgcn_perm(B.u + 0x8000u, A.u + 0x8000u, 0x07060302u);
}

// ---------------------------------------------------------------- convert
// one float4 per thread; grid must be exactly nElems/4/256 blocks
__global__ __launch_bounds__(256) void cvt_kernel(const float* __restrict__ src,
                                                  short* __restrict__ dst) {
    int i = blockIdx.x * 256 + threadIdx.x;
    float4 v = ((const float4*)src)[i];
    bf16x4 o; o.x = f2bf(v.x); o.y = f2bf(v.y); o.z = f2bf(v.z); o.w = f2bf(v.w);
    ((bf16x4*)dst)[i] = o;
}

// ------------------------------------------------- weight transpose W[k][n] -> WT[n][k] bf16
__global__ __launch_bounds__(256) void wtrans_kernel(const float* __restrict__ Wq,
                                                     const float* __restrict__ Wk,
                                                     const float* __restrict__ Wv,
                                                     const float* __restrict__ Wo,
                                                     short* __restrict__ wT) {
    __shared__ float tile[32][33];
    const float* W = (blockIdx.z == 0) ? Wq : (blockIdx.z == 1) ? Wk
                   : (blockIdx.z == 2) ? Wv : Wo;
    short* dst = wT + (size_t)blockIdx.z * DIMK * DIMK;
    int n0 = blockIdx.x * 32, k0 = blockIdx.y * 32;
    int tx = threadIdx.x, ty = threadIdx.y;          // (32,8)
#pragma unroll
    for (int i = 0; i < 32; i += 8)
        tile[ty + i][tx] = W[(size_t)(k0 + ty + i) * DIMK + n0 + tx];
    __syncthreads();
#pragma unroll
    for (int i = 0; i < 32; i += 8)
        dst[(size_t)(n0 + ty + i) * DIMK + k0 + tx] = f2bf(tile[tx][ty + i]);
}

// ---------------------------------------------------------------- GEMM mainloop
// C(128x64) = A(128x512) @ BT(64x512)^T, bf16 in, fp32 acc. 4 waves, each 32x64.
__device__ __forceinline__ void gemm_mainloop(const short* __restrict__ Ablk,
                                              const short* __restrict__ Bblk,
                                              short* sA, short* sB, fx4 acc[2][4]) {
    int t = threadIdx.x;
    int w = t >> 6, lane = t & 63, quad = (lane >> 4), l15 = lane & 15;
    for (int k0 = 0; k0 < DIMK; k0 += 32) {
        __syncthreads();
        // stage A 128x32 (two passes), B 64x32
#pragma unroll
        for (int i = 0; i < 2; i++) {
            int row = i * 64 + (t >> 2), c = t & 3;
            *(bf16x8*)&sA[row * 32 + c * 8] =
                *(const bf16x8*)&Ablk[(size_t)row * DIMK + k0 + c * 8];
        }
        {
            int row = t >> 2, c = t & 3;
            *(bf16x8*)&sB[row * 32 + c * 8] =
                *(const bf16x8*)&Bblk[(size_t)row * DIMK + k0 + c * 8];
        }
        __syncthreads();
        bf16x8 a[2], b[4];
#pragma unroll
        for (int mt = 0; mt < 2; mt++)
            a[mt] = *(bf16x8*)&sA[(w * 32 + mt * 16 + l15) * 32 + quad * 8];
#pragma unroll
        for (int nt = 0; nt < 4; nt++)
            b[nt] = *(bf16x8*)&sB[(nt * 16 + l15) * 32 + quad * 8];
#pragma unroll
        for (int mt = 0; mt < 2; mt++)
#pragma unroll
            for (int nt = 0; nt < 4; nt++)
                acc[mt][nt] = __builtin_amdgcn_mfma_f32_16x16x32_bf16(
                    a[mt], b[nt], acc[mt][nt], 0, 0, 0);
    }
}

// ---------------------------------------------------------------- QKV projection
// mode(z): 0 -> q[bh][n][64], 1 -> k[bh][j][64], 2 -> vT[bh][64][2048]
__global__ __launch_bounds__(256) void proj_qkv(const short* __restrict__ xb,
                                                const short* __restrict__ mb,
                                                const short* __restrict__ wT,
                                                short* __restrict__ qkv) {
    __shared__ __attribute__((aligned(16))) short sA[128 * 32];
    __shared__ __attribute__((aligned(16))) short sB[64 * 32];
    int mode = blockIdx.z;
    const short* A  = ((mode == 0) ? xb : mb) + (size_t)blockIdx.x * 128 * DIMK;
    const short* BT = wT + (size_t)mode * DIMK * DIMK + (size_t)blockIdx.y * 64 * DIMK;
    fx4 acc[2][4] = {};
    gemm_mainloop(A, BT, sA, sB, acc);

    int t = threadIdx.x, w = t >> 6, lane = t & 63, quad = lane >> 4, l15 = lane & 15;
    int h = blockIdx.y;                              // 512 cols / 64 per block -> h == y
    short* dst = qkv + (size_t)mode * MROWS * DIMK;
#pragma unroll
    for (int mt = 0; mt < 2; mt++)
#pragma unroll
        for (int nt = 0; nt < 4; nt++)
#pragma unroll
            for (int r = 0; r < 4; r++) {
                int gm = blockIdx.x * 128 + w * 32 + mt * 16 + quad * 4 + r;
                int b = gm >> 11, n = gm & 2047;
                int d = nt * 16 + l15;
                short val = f2bf(acc[mt][nt][r]);
                if (mode < 2)
                    dst[(((size_t)(b * 8 + h) * SEQ + n) << 6) + d] = val;
                else
                    dst[(((size_t)(b * 8 + h) * DHEAD + d) << 11) + n] = val;
            }
}

// ---------------------------------------------------------------- output projection
__global__ __launch_bounds__(256) void out_proj(const short* __restrict__ ob,
                                                const short* __restrict__ woT,
                                                const float* __restrict__ bo,
                                                float* __restrict__ out) {
    __shared__ __attribute__((aligned(16))) short sA[128 * 32];
    __shared__ __attribute__((aligned(16))) short sB[64 * 32];
    const short* A  = ob + (size_t)blockIdx.x * 128 * DIMK;
    const short* BT = woT + (size_t)blockIdx.y * 64 * DIMK;
    fx4 acc[2][4] = {};
    gemm_mainloop(A, BT, sA, sB, acc);

    int t = threadIdx.x, w = t >> 6, lane = t & 63, quad = lane >> 4, l15 = lane & 15;
#pragma unroll
    for (int mt = 0; mt < 2; mt++)
#pragma unroll
        for (int nt = 0; nt < 4; nt++) {
            int gn = blockIdx.y * 64 + nt * 16 + l15;
            float bias = bo[gn];
#pragma unroll
            for (int r = 0; r < 4; r++) {
                int gm = blockIdx.x * 128 + w * 32 + mt * 16 + quad * 4 + r;
                out[(size_t)gm * DIMK + gn] = acc[mt][nt][r] + bias;
            }
        }
}

// ---------------------------------------------------------------- flash attention (S^T form)
// grid: (SEQ/128, BATCH*HEADS). block 256 = 4 waves; wave w owns q rows [i0+32w, i0+32w+32).
// Computes S^T = K @ Q^T so each lane holds complete softmax rows (i = lane&15),
// then O^T = V^T @ P^T so the epilogue is d-contiguous vector stores.
__global__ __launch_bounds__(256, 4) void attn_kernel(const short* __restrict__ q,
                                                      const short* __restrict__ k,
                                                      const short* __restrict__ vt,
                                                      short* __restrict__ o) {
    // sK/sV: 64 rows x 72; sQ: 128 rows x 72 (aliased per-wave as sP after Q prefetch)
    __shared__ __attribute__((aligned(16))) short lds[2 * 64 * LDSS + 128 * LDSS];
    short* sK = lds;
    short* sV = lds + 64 * LDSS;
    short* sQ = lds + 2 * 64 * LDSS;

    int t = threadIdx.x, w = t >> 6, lane = t & 63, quad = lane >> 4, l15 = lane & 15;
    int bh = blockIdx.y;
    int i0 = blockIdx.x * 128;
    const short* qbh = q  + (size_t)bh * SEQ * DHEAD;
    const short* kbh = k  + (size_t)bh * SEQ * DHEAD;
    const short* vbh = vt + (size_t)bh * DHEAD * SEQ;

    // stage Q (128x64) into padded LDS
#pragma unroll
    for (int i = 0; i < 4; i++) {
        int idx = i * 256 + t, row = idx >> 3, c = idx & 7;
        *(bf16x8*)&sQ[row * LDSS + c * 8] =
            *(const bf16x8*)&qbh[(size_t)(i0 + row) * DHEAD + c * 8];
    }
    __syncthreads();
    // Q fragments: double duty as the B-operand of S^T = K @ Q^T
    bf16x8 aq[2][2];
#pragma unroll
    for (int it = 0; it < 2; it++)
#pragma unroll
        for (int ks = 0; ks < 2; ks++)
            aq[it][ks] = *(bf16x8*)&sQ[(w * 32 + it * 16 + l15) * LDSS + ks * 32 + quad * 8];
    // per-wave P buffer aliases this wave's (now consumed) Q rows
    short* sP = sQ + w * 32 * LDSS;

    float mrun[2] = {-3e38f, -3e38f}, lrun[2] = {0.f, 0.f};
    fx4 oacc[2][4] = {};

    for (int j0 = 0; j0 < SEQ; j0 += 64) {
        __syncthreads();   // prior iteration's sK/sV fragment reads complete
#pragma unroll
        for (int i = 0; i < 2; i++) {
            int idx = i * 256 + t, row = idx >> 3, c = idx & 7;
            *(bf16x8*)&sK[row * LDSS + c * 8] =
                *(const bf16x8*)&kbh[(size_t)(j0 + row) * DHEAD + c * 8];
            *(bf16x8*)&sV[row * LDSS + c * 8] =
                *(const bf16x8*)&vbh[(size_t)row * SEQ + j0 + c * 8];
        }
        __syncthreads();

        // S^T = K @ Q^T : lane holds S[i = it*16+l15][j = jt*16 + quad*4 + r]
        fx4 s[2][4];
#pragma unroll
        for (int jt = 0; jt < 4; jt++) {
            bf16x8 ak0 = *(bf16x8*)&sK[(jt * 16 + l15) * LDSS + quad * 8];
            bf16x8 ak1 = *(bf16x8*)&sK[(jt * 16 + l15) * LDSS + 32 + quad * 8];
#pragma unroll
            for (int it = 0; it < 2; it++) {
                fx4 z = {0.f, 0.f, 0.f, 0.f};
                z = __builtin_amdgcn_mfma_f32_16x16x32_bf16(ak0, aq[it][0], z, 0, 0, 0);
                z = __builtin_amdgcn_mfma_f32_16x16x32_bf16(ak1, aq[it][1], z, 0, 0, 0);
                s[it][jt] = z;
            }
        }

        // online softmax: full row per lane (+2 cross-quad shuffles)
#pragma unroll
        for (int it = 0; it < 2; it++) {
            float mx = s[it][0][0];
#pragma unroll
            for (int jt = 0; jt < 4; jt++)
#pragma unroll
                for (int r = 0; r < 4; r++) mx = fmaxf(mx, s[it][jt][r]);
            mx = fmaxf(mx, __shfl_xor(mx, 16));
            mx = fmaxf(mx, __shfl_xor(mx, 32));
            float mn = fmaxf(mrun[it], mx * SCALE_LOG2E);
            float alpha = __builtin_amdgcn_exp2f(mrun[it] - mn);
            mrun[it] = mn;
            float sum = 0.f;
#pragma unroll
            for (int jt = 0; jt < 4; jt++) {
                float p0 = __builtin_amdgcn_exp2f(s[it][jt][0] * SCALE_LOG2E - mn);
                float p1 = __builtin_amdgcn_exp2f(s[it][jt][1] * SCALE_LOG2E - mn);
                float p2 = __builtin_amdgcn_exp2f(s[it][jt][2] * SCALE_LOG2E - mn);
                float p3 = __builtin_amdgcn_exp2f(s[it][jt][3] * SCALE_LOG2E - mn);
                sum += (p0 + p1) + (p2 + p3);
                uint2 pv; pv.x = pk2bf(p0, p1); pv.y = pk2bf(p2, p3);
                *(uint2*)&sP[(it * 16 + l15) * LDSS + jt * 16 + quad * 4] = pv;
            }
            sum += __shfl_xor(sum, 16);
            sum += __shfl_xor(sum, 32);
            lrun[it] = lrun[it] * alpha + sum;
#pragma unroll
            for (int dt = 0; dt < 4; dt++)
#pragma unroll
                for (int r = 0; r < 4; r++) oacc[it][dt][r] *= alpha;
        }

        // P^T fragments (wave-local LDS round-trip, no barrier needed)
        bf16x8 bp[2][2];
#pragma unroll
        for (int it = 0; it < 2; it++)
#pragma unroll
            for (int ks = 0; ks < 2; ks++)
                bp[it][ks] = *(bf16x8*)&sP[(it * 16 + l15) * LDSS + ks * 32 + quad * 8];

        // O^T += V^T @ P^T
#pragma unroll
        for (int dt = 0; dt < 4; dt++) {
            bf16x8 av0 = *(bf16x8*)&sV[(dt * 16 + l15) * LDSS + quad * 8];
            bf16x8 av1 = *(bf16x8*)&sV[(dt * 16 + l15) * LDSS + 32 + quad * 8];
#pragma unroll
            for (int it = 0; it < 2; it++) {
                oacc[it][dt] = __builtin_amdgcn_mfma_f32_16x16x32_bf16(av0, bp[it][0], oacc[it][dt], 0, 0, 0);
                oacc[it][dt] = __builtin_amdgcn_mfma_f32_16x16x32_bf16(av1, bp[it][1], oacc[it][dt], 0, 0, 0);
            }
        }
    }

    // epilogue: lane holds O[i = it*16+l15][d = dt*16 + quad*4 + r] -> d-contiguous b64 stores
    int b = bh >> 3, h = bh & 7;
#pragma unroll
    for (int it = 0; it < 2; it++) {
        float rl = 1.0f / lrun[it];
        int i = i0 + w * 32 + it * 16 + l15;
        size_t base = ((size_t)(b * SEQ + i) * DIMK) + h * DHEAD;
#pragma unroll
        for (int dt = 0; dt < 4; dt++) {
            uint2 pv;
            pv.x = pk2bf(oacc[it][dt][0] * rl, oacc[it][dt][1] * rl);
            pv.y = pk2bf(oacc[it][dt][2] * rl, oacc[it][dt][3] * rl);
            *(uint2*)&o[base + dt * 16 + quad * 4] = pv;
        }
    }
}

// ---------------------------------------------------------------- launch
extern "C" void kernel_launch(void* const* d_in, const int* in_sizes, int n_in,
                              void* d_out, int out_size, void* d_ws, size_t ws_size,
                              hipStream_t stream) {
    const float* x  = (const float*)d_in[0];
    const float* m  = (const float*)d_in[1];
    const float* Wq = (const float*)d_in[2];
    const float* Wk = (const float*)d_in[3];
    const float* Wv = (const float*)d_in[4];
    const float* Wo = (const float*)d_in[5];
    const float* bo = (const float*)d_in[6];
    float* out = (float*)d_out;

    char* ws = (char*)d_ws;
    const size_t XB_BYTES = (size_t)MROWS * DIMK * 2;      // 16 MiB
    short* xb  = (short*)(ws);
    short* mb  = (short*)(ws + XB_BYTES);
    short* wT  = (short*)(ws + 2 * XB_BYTES);              // 4 x 512x512 bf16 = 2 MiB
    short* qkv = (short*)(ws + 2 * XB_BYTES + 4 * (size_t)DIMK * DIMK * 2);
    short* ob  = xb;   // xb is dead after proj_qkv; reuse as attention output

    // x,m each have MROWS*DIMK = 8,388,608 floats = 2,097,152 float4 -> 8192 blocks
    const int CVT_BLOCKS = (MROWS * DIMK) / 4 / 256;       // 8192
    cvt_kernel<<<CVT_BLOCKS, 256, 0, stream>>>(x, xb);
    cvt_kernel<<<CVT_BLOCKS, 256, 0, stream>>>(m, mb);
    wtrans_kernel<<<dim3(16, 16, 4), dim3(32, 8), 0, stream>>>(Wq, Wk, Wv, Wo, wT);
    proj_qkv<<<dim3(128, 8, 3), 256, 0, stream>>>(xb, mb, wT, qkv);
    attn_kernel<<<dim3(SEQ / 128, BATCH * HEADS), 256, 0, stream>>>(
        qkv, qkv + (size_t)MROWS * DIMK, qkv + 2 * (size_t)MROWS * DIMK, ob);
    out_proj<<<dim3(128, 8), 256, 0, stream>>>(ob, wT + 3 * (size_t)DIMK * DIMK, bo, out);
}